// Round 1
// baseline (211.481 us; speedup 1.0000x reference)
//
#include <hip/hip_runtime.h>

#define BB 8
#define LL 4096
#define DM 64
#define DI 128
#define NS 16
#define TCH 128
#define NCH 32   // LL/TCH

__device__ __forceinline__ float siluf(float x) {
  return x / (1.f + __expf(-x));
}
__device__ __forceinline__ float softplusf(float x) {
  return x > 20.f ? x : log1pf(__expf(x));
}

// ---------------- K1: in_proj  xr = x @ Win^T ; u_pre = xr[:, :128]; gate = silu(xr[:, 128:])
__global__ __launch_bounds__(256) void k_inproj(
    const float* __restrict__ x, const float* __restrict__ Win,
    float* __restrict__ upre, float* __restrict__ gate) {
  __shared__ float xs[64][132];   // [k][t]
  __shared__ float wT[64][264];   // [k][j]
  const int b = blockIdx.x >> 5;
  const int l0 = (blockIdx.x & 31) * TCH;
  const int tid = threadIdx.x;
  // stage x tile transposed: 128 tok x 64 k
  for (int i = 0; i < 8; ++i) {
    int idx = (i * 256 + tid) * 4;
    int t = idx >> 6, k = idx & 63;
    float4 v = *(const float4*)(x + ((size_t)b * LL + l0 + t) * DM + k);
    xs[k][t] = v.x; xs[k + 1][t] = v.y; xs[k + 2][t] = v.z; xs[k + 3][t] = v.w;
  }
  // stage Win transposed: 256 j x 64 k
  for (int i = 0; i < 16; ++i) {
    int idx = (i * 256 + tid) * 4;
    int j = idx >> 6, k = idx & 63;
    float4 v = *(const float4*)(Win + idx);
    wT[k][j] = v.x; wT[k + 1][j] = v.y; wT[k + 2][j] = v.z; wT[k + 3][j] = v.w;
  }
  __syncthreads();
  const int tg = (tid >> 4) * 8;   // token base (8 tokens per thread)
  const int jgb = (tid & 15) * 8;  // j base (8 outputs per thread)
  for (int jl = 0; jl < 2; ++jl) {
    const int j0 = jgb + jl * 128;
    float acc[8][8];
#pragma unroll
    for (int i = 0; i < 8; ++i)
#pragma unroll
      for (int j = 0; j < 8; ++j) acc[i][j] = 0.f;
    for (int k = 0; k < 64; ++k) {
      float av[8], wv[8];
      *(float4*)&av[0] = *(const float4*)&xs[k][tg];
      *(float4*)&av[4] = *(const float4*)&xs[k][tg + 4];
      *(float4*)&wv[0] = *(const float4*)&wT[k][j0];
      *(float4*)&wv[4] = *(const float4*)&wT[k][j0 + 4];
#pragma unroll
      for (int i = 0; i < 8; ++i)
#pragma unroll
        for (int j = 0; j < 8; ++j) acc[i][j] = fmaf(av[i], wv[j], acc[i][j]);
    }
    for (int i = 0; i < 8; ++i) {
      size_t row = ((size_t)b * LL + l0 + tg + i);
      if (jl == 0) {
        *(float4*)(upre + row * DI + j0) =
            make_float4(acc[i][0], acc[i][1], acc[i][2], acc[i][3]);
        *(float4*)(upre + row * DI + j0 + 4) =
            make_float4(acc[i][4], acc[i][5], acc[i][6], acc[i][7]);
      } else {
        int g0 = j0 - 128;
        *(float4*)(gate + row * DI + g0) =
            make_float4(siluf(acc[i][0]), siluf(acc[i][1]), siluf(acc[i][2]), siluf(acc[i][3]));
        *(float4*)(gate + row * DI + g0 + 4) =
            make_float4(siluf(acc[i][4]), siluf(acc[i][5]), siluf(acc[i][6]), siluf(acc[i][7]));
      }
    }
  }
}

// ---------------- K2: conv+silu -> u; x_proj -> (dr, B, C); dt_proj+softplus -> delta; local chunk scan
__global__ __launch_bounds__(256) void k_mid(
    const float* __restrict__ upre,
    const float* __restrict__ convw, const float* __restrict__ convb,
    const float* __restrict__ xpw, const float* __restrict__ dtw,
    const float* __restrict__ dtb, const float* __restrict__ Alog,
    float* __restrict__ u_g, float* __restrict__ delta_g,
    float* __restrict__ Bm_g, float* __restrict__ Cm_g,
    float* __restrict__ Aprod, float* __restrict__ Hend) {
  __shared__ float us[TCH][132];
  __shared__ float ds[TCH][132];
  __shared__ float drs[TCH][4];
  __shared__ float bs[TCH][16];
  const int b = blockIdx.x >> 5;
  const int c = blockIdx.x & 31;
  const int l0 = c * TCH;
  const int tid = threadIdx.x;
  // P0: depthwise conv(4) + bias + silu
  for (int i = 0; i < 16; ++i) {
    int idx = i * 256 + tid;
    int t = idx >> 5, d = (idx & 31) * 4;
    float4 cb = *(const float4*)(convb + d);
    float a0 = cb.x, a1 = cb.y, a2 = cb.z, a3 = cb.w;
#pragma unroll
    for (int k = 0; k < 4; ++k) {
      int lt = l0 + t - 3 + k;
      if (lt >= 0) {
        const float4 up = *(const float4*)(upre + ((size_t)b * LL + lt) * DI + d);
        a0 = fmaf(up.x, convw[(d + 0) * 4 + k], a0);
        a1 = fmaf(up.y, convw[(d + 1) * 4 + k], a1);
        a2 = fmaf(up.z, convw[(d + 2) * 4 + k], a2);
        a3 = fmaf(up.w, convw[(d + 3) * 4 + k], a3);
      }
    }
    float4 uv = make_float4(siluf(a0), siluf(a1), siluf(a2), siluf(a3));
    *(float4*)&us[t][d] = uv;
    *(float4*)(u_g + ((size_t)b * LL + l0 + t) * DI + d) = uv;
  }
  __syncthreads();
  // P1: dbl = u @ xpw^T  (36 outputs/token)
  {
    const int t = tid & 127;
    const int jg = __builtin_amdgcn_readfirstlane((tid >> 7) & 1);
    float acc[18];
#pragma unroll
    for (int jj = 0; jj < 18; ++jj) acc[jj] = 0.f;
    for (int k = 0; k < 128; k += 4) {
      float4 uv = *(const float4*)&us[t][k];
#pragma unroll
      for (int jj = 0; jj < 18; ++jj) {
        float4 w = *(const float4*)(xpw + (2 * jj + jg) * DI + k);
        acc[jj] = fmaf(uv.x, w.x, acc[jj]);
        acc[jj] = fmaf(uv.y, w.y, acc[jj]);
        acc[jj] = fmaf(uv.z, w.z, acc[jj]);
        acc[jj] = fmaf(uv.w, w.w, acc[jj]);
      }
    }
    size_t tok = (size_t)b * LL + l0 + t;
#pragma unroll
    for (int jj = 0; jj < 18; ++jj) {
      int j = 2 * jj + jg;
      if (j < 4) drs[t][j] = acc[jj];
      else if (j < 20) { bs[t][j - 4] = acc[jj]; Bm_g[tok * NS + j - 4] = acc[jj]; }
      else Cm_g[tok * NS + j - 20] = acc[jj];
    }
  }
  __syncthreads();
  // P2: delta = softplus(dr @ dtw^T + dtb)
  for (int i = 0; i < 16; ++i) {
    int idx = i * 256 + tid;
    int t = idx >> 5, d = (idx & 31) * 4;
    float4 dr = *(const float4*)&drs[t][0];
    float4 ov;
    float* po = &ov.x;
#pragma unroll
    for (int m = 0; m < 4; ++m) {
      float4 w = *(const float4*)(dtw + (d + m) * 4);
      float v = dr.x * w.x + dr.y * w.y + dr.z * w.z + dr.w * w.w + dtb[d + m];
      po[m] = softplusf(v);
    }
    *(float4*)&ds[t][d] = ov;
    *(float4*)(delta_g + ((size_t)b * LL + l0 + t) * DI + d) = ov;
  }
  __syncthreads();
  // P3: local chunk scan (zero initial state) -> Aprod, Hend
  {
    const int d = tid >> 1;
    const int n0 = (tid & 1) * 8;
    float a[8], h[8], ap[8];
#pragma unroll
    for (int m = 0; m < 8; ++m) {
      a[m] = -__expf(Alog[d * NS + n0 + m]);
      h[m] = 0.f; ap[m] = 1.f;
    }
    for (int l = 0; l < TCH; ++l) {
      float dl = ds[l][d];
      float du = dl * us[l][d];
#pragma unroll
      for (int m = 0; m < 8; ++m) {
        float dA = __expf(dl * a[m]);
        ap[m] *= dA;
        h[m] = fmaf(dA, h[m], du * bs[l][n0 + m]);
      }
    }
    size_t base = ((size_t)(b * NCH + c) * DI + d) * NS + n0;
    *(float4*)(Aprod + base) = make_float4(ap[0], ap[1], ap[2], ap[3]);
    *(float4*)(Aprod + base + 4) = make_float4(ap[4], ap[5], ap[6], ap[7]);
    *(float4*)(Hend + base) = make_float4(h[0], h[1], h[2], h[3]);
    *(float4*)(Hend + base + 4) = make_float4(h[4], h[5], h[6], h[7]);
  }
}

// ---------------- K3: prefix over chunks (per (b,d,n) channel)
__global__ __launch_bounds__(256) void k_prefix(
    const float* __restrict__ Aprod, const float* __restrict__ Hend,
    float* __restrict__ Hin) {
  int i = blockIdx.x * 256 + threadIdx.x;  // 16384 channels
  int b = i >> 11, dn = i & 2047;
  float h = 0.f;
  for (int c = 0; c < NCH; ++c) {
    size_t idx = (size_t)(b * NCH + c) * 2048 + dn;
    Hin[idx] = h;
    h = fmaf(Aprod[idx], h, Hend[idx]);
  }
}

// ---------------- K4: final scan with Hin + y = (sum h*C + u*D) * gate; out = y @ Wout^T
__global__ __launch_bounds__(256) void k_final(
    const float* __restrict__ u_g, const float* __restrict__ delta_g,
    const float* __restrict__ Bm_g, const float* __restrict__ Cm_g,
    const float* __restrict__ gate, const float* __restrict__ Hin,
    const float* __restrict__ Alog, const float* __restrict__ Dw,
    const float* __restrict__ Wout, float* __restrict__ out) {
  __shared__ float yst[DI][132];  // [d][t]
  __shared__ float wot[DI][68];   // [d][o]
  const int b = blockIdx.x >> 5;
  const int c = blockIdx.x & 31;
  const int l0 = c * TCH;
  const int tid = threadIdx.x;
  // stage Wout transposed
  for (int i = 0; i < 8; ++i) {
    int idx = (i * 256 + tid) * 4;
    int o = idx >> 7, d = idx & 127;
    float4 v = *(const float4*)(Wout + idx);
    wot[d][o] = v.x; wot[d + 1][o] = v.y; wot[d + 2][o] = v.z; wot[d + 3][o] = v.w;
  }
  const int d = tid >> 1;
  const int n0 = (tid & 1) * 8;
  float a[8], h[8];
  size_t hbase = ((size_t)(b * NCH + c) * DI + d) * NS + n0;
#pragma unroll
  for (int m = 0; m < 8; ++m) {
    a[m] = -__expf(Alog[d * NS + n0 + m]);
    h[m] = Hin[hbase + m];
  }
  float Dd = Dw[d];
  __syncthreads();
  for (int l = 0; l < TCH; ++l) {
    size_t tok = (size_t)b * LL + l0 + l;
    float dl = delta_g[tok * DI + d];
    float uu = u_g[tok * DI + d];
    float du = dl * uu;
    const float* bp = Bm_g + tok * NS + n0;
    const float* cp = Cm_g + tok * NS + n0;
    float py = 0.f;
#pragma unroll
    for (int m = 0; m < 8; ++m) {
      float dA = __expf(dl * a[m]);
      h[m] = fmaf(dA, h[m], du * bp[m]);
      py = fmaf(h[m], cp[m], py);
    }
    py += __shfl_xor(py, 1);
    if ((tid & 1) == 0) {
      yst[d][l] = (py + uu * Dd) * gate[tok * DI + d];
    }
  }
  __syncthreads();
  // epilogue: out[t][o] = sum_d y[t][d] * Wout[o][d]; 8 tok x 4 out per thread
  const int t0 = (tid >> 4) * 8;
  const int o0 = (tid & 15) * 4;
  float acc[8][4];
#pragma unroll
  for (int i = 0; i < 8; ++i)
#pragma unroll
    for (int j = 0; j < 4; ++j) acc[i][j] = 0.f;
  for (int dd = 0; dd < DI; ++dd) {
    float yv[8], wv[4];
    *(float4*)&yv[0] = *(const float4*)&yst[dd][t0];
    *(float4*)&yv[4] = *(const float4*)&yst[dd][t0 + 4];
    *(float4*)&wv[0] = *(const float4*)&wot[dd][o0];
#pragma unroll
    for (int i = 0; i < 8; ++i)
#pragma unroll
      for (int j = 0; j < 4; ++j) acc[i][j] = fmaf(yv[i], wv[j], acc[i][j]);
  }
  for (int i = 0; i < 8; ++i) {
    size_t row = (size_t)b * LL + l0 + t0 + i;
    *(float4*)(out + row * DM + o0) =
        make_float4(acc[i][0], acc[i][1], acc[i][2], acc[i][3]);
  }
}

extern "C" void kernel_launch(void* const* d_in, const int* in_sizes, int n_in,
                              void* d_out, int out_size, void* d_ws, size_t ws_size,
                              hipStream_t stream) {
  const float* x     = (const float*)d_in[0];
  // d_in[1] = latent (unused by reference)
  const float* Win   = (const float*)d_in[2];
  const float* convw = (const float*)d_in[3];
  const float* convb = (const float*)d_in[4];
  const float* xpw   = (const float*)d_in[5];
  const float* dtw   = (const float*)d_in[6];
  const float* dtb   = (const float*)d_in[7];
  const float* Wout  = (const float*)d_in[8];
  const float* Alog  = (const float*)d_in[9];
  const float* Dw    = (const float*)d_in[10];
  float* ws = (float*)d_ws;
  const size_t NT = (size_t)BB * LL;  // 32768 tokens
  float* upre    = ws;
  float* gate    = upre + NT * DI;
  float* u_g     = gate + NT * DI;
  float* delta_g = u_g + NT * DI;
  float* Bm_g    = delta_g + NT * DI;
  float* Cm_g    = Bm_g + NT * NS;
  float* Aprod   = Cm_g + NT * NS;
  float* Hend    = Aprod + (size_t)BB * NCH * DI * NS;
  float* Hin     = Hend + (size_t)BB * NCH * DI * NS;
  float* outf = (float*)d_out;

  k_inproj<<<256, 256, 0, stream>>>(x, Win, upre, gate);
  k_mid<<<256, 256, 0, stream>>>(upre, convw, convb, xpw, dtw, dtb, Alog,
                                 u_g, delta_g, Bm_g, Cm_g, Aprod, Hend);
  k_prefix<<<64, 256, 0, stream>>>(Aprod, Hend, Hin);
  k_final<<<256, 256, 0, stream>>>(u_g, delta_g, Bm_g, Cm_g, gate, Hin,
                                   Alog, Dw, Wout, outf);
}

// Round 2
// 202.360 us; speedup vs baseline: 1.0451x; 1.0451x over previous
//
#include <hip/hip_runtime.h>

#define BB 8
#define LL 4096
#define DM 64
#define DI 128
#define NS 16
#define TCH 32
#define NCH 128   // LL/TCH

__device__ __forceinline__ float siluf(float x) {
  return x / (1.f + __expf(-x));
}
__device__ __forceinline__ float softplusf(float x) {
  return x > 20.f ? x : log1pf(__expf(x));
}

// ---------------- K1: in_proj  xr = x @ Win^T ; upre = xr[:, :128]; gate = silu(xr[:, 128:])
// 512 blocks: (b, 32 token-chunks of 128, 2 j-halves). LDS 67.6KB -> 2 blocks/CU.
__global__ __launch_bounds__(256) void k_inproj(
    const float* __restrict__ x, const float* __restrict__ Win,
    float* __restrict__ upre, float* __restrict__ gate) {
  __shared__ float xs[64][132];   // [k][t]
  __shared__ float wT[64][132];   // [k][j]
  const int bid = blockIdx.x;
  const int jh = bid & 1;
  const int lc = (bid >> 1) & 31;
  const int b  = bid >> 6;
  const int l0 = lc * 128;
  const int tid = threadIdx.x;
  for (int i = 0; i < 8; ++i) {
    int idx = (i * 256 + tid) * 4;
    int t = idx >> 6, k = idx & 63;
    float4 v = *(const float4*)(x + ((size_t)b * LL + l0 + t) * DM + k);
    xs[k][t] = v.x; xs[k + 1][t] = v.y; xs[k + 2][t] = v.z; xs[k + 3][t] = v.w;
  }
  for (int i = 0; i < 8; ++i) {
    int idx = (i * 256 + tid) * 4;
    int j = idx >> 6, k = idx & 63;
    float4 v = *(const float4*)(Win + (size_t)(jh * 128 + j) * DM + k);
    wT[k][j] = v.x; wT[k + 1][j] = v.y; wT[k + 2][j] = v.z; wT[k + 3][j] = v.w;
  }
  __syncthreads();
  const int tg = (tid >> 4) * 8;
  const int j0 = (tid & 15) * 8;
  float acc[8][8];
#pragma unroll
  for (int i = 0; i < 8; ++i)
#pragma unroll
    for (int j = 0; j < 8; ++j) acc[i][j] = 0.f;
  for (int k = 0; k < 64; ++k) {
    float av[8], wv[8];
    *(float4*)&av[0] = *(const float4*)&xs[k][tg];
    *(float4*)&av[4] = *(const float4*)&xs[k][tg + 4];
    *(float4*)&wv[0] = *(const float4*)&wT[k][j0];
    *(float4*)&wv[4] = *(const float4*)&wT[k][j0 + 4];
#pragma unroll
    for (int i = 0; i < 8; ++i)
#pragma unroll
      for (int j = 0; j < 8; ++j) acc[i][j] = fmaf(av[i], wv[j], acc[i][j]);
  }
  for (int i = 0; i < 8; ++i) {
    size_t row = ((size_t)b * LL + l0 + tg + i);
    if (jh == 0) {
      *(float4*)(upre + row * DI + j0) =
          make_float4(acc[i][0], acc[i][1], acc[i][2], acc[i][3]);
      *(float4*)(upre + row * DI + j0 + 4) =
          make_float4(acc[i][4], acc[i][5], acc[i][6], acc[i][7]);
    } else {
      *(float4*)(gate + row * DI + j0) =
          make_float4(siluf(acc[i][0]), siluf(acc[i][1]), siluf(acc[i][2]), siluf(acc[i][3]));
      *(float4*)(gate + row * DI + j0 + 4) =
          make_float4(siluf(acc[i][4]), siluf(acc[i][5]), siluf(acc[i][6]), siluf(acc[i][7]));
    }
  }
}

// ---------------- K2: conv+silu -> u_g; x_proj -> (dr, Bm, Cm); dt_proj+softplus -> delta_g
// 512 blocks: (b, 64 token-chunks of 64). LDS ~35KB.
__global__ __launch_bounds__(256) void k_front(
    const float* __restrict__ upre,
    const float* __restrict__ convw, const float* __restrict__ convb,
    const float* __restrict__ xpw, const float* __restrict__ dtw,
    const float* __restrict__ dtb,
    float* __restrict__ u_g, float* __restrict__ delta_g,
    float* __restrict__ Bm_g, float* __restrict__ Cm_g) {
  __shared__ float us[64][132];
  __shared__ float drs[64][4];
  const int b = blockIdx.x >> 6;
  const int l0 = (blockIdx.x & 63) * 64;
  const int tid = threadIdx.x;
  // conv(4) + bias + silu
  for (int i = 0; i < 8; ++i) {
    int idx = i * 256 + tid;
    int t = idx >> 5, d = (idx & 31) * 4;
    float4 cb = *(const float4*)(convb + d);
    float a0 = cb.x, a1 = cb.y, a2 = cb.z, a3 = cb.w;
#pragma unroll
    for (int k = 0; k < 4; ++k) {
      int lt = l0 + t - 3 + k;
      if (lt >= 0) {
        const float4 up = *(const float4*)(upre + ((size_t)b * LL + lt) * DI + d);
        a0 = fmaf(up.x, convw[(d + 0) * 4 + k], a0);
        a1 = fmaf(up.y, convw[(d + 1) * 4 + k], a1);
        a2 = fmaf(up.z, convw[(d + 2) * 4 + k], a2);
        a3 = fmaf(up.w, convw[(d + 3) * 4 + k], a3);
      }
    }
    float4 uv = make_float4(siluf(a0), siluf(a1), siluf(a2), siluf(a3));
    *(float4*)&us[t][d] = uv;
    *(float4*)(u_g + ((size_t)b * LL + l0 + t) * DI + d) = uv;
  }
  __syncthreads();
  // x_proj: 4 threads per token x 9 outputs
  {
    const int t = tid >> 2;
    const int jg = tid & 3;
    float acc[9];
#pragma unroll
    for (int jj = 0; jj < 9; ++jj) acc[jj] = 0.f;
    for (int k = 0; k < 128; k += 4) {
      float4 uv = *(const float4*)&us[t][k];
#pragma unroll
      for (int jj = 0; jj < 9; ++jj) {
        float4 w = *(const float4*)(xpw + (size_t)(jg * 9 + jj) * DI + k);
        acc[jj] = fmaf(uv.x, w.x, acc[jj]);
        acc[jj] = fmaf(uv.y, w.y, acc[jj]);
        acc[jj] = fmaf(uv.z, w.z, acc[jj]);
        acc[jj] = fmaf(uv.w, w.w, acc[jj]);
      }
    }
    size_t tok = (size_t)b * LL + l0 + t;
#pragma unroll
    for (int jj = 0; jj < 9; ++jj) {
      int j = jg * 9 + jj;
      if (j < 4) drs[t][j] = acc[jj];
      else if (j < 20) Bm_g[tok * NS + j - 4] = acc[jj];
      else Cm_g[tok * NS + j - 20] = acc[jj];
    }
  }
  __syncthreads();
  // dt_proj + softplus
  for (int i = 0; i < 8; ++i) {
    int idx = i * 256 + tid;
    int t = idx >> 5, d = (idx & 31) * 4;
    float4 dr = *(const float4*)&drs[t][0];
    float4 ov;
    float* po = &ov.x;
#pragma unroll
    for (int m = 0; m < 4; ++m) {
      float4 w = *(const float4*)(dtw + (size_t)(d + m) * 4);
      float v = dr.x * w.x + dr.y * w.y + dr.z * w.z + dr.w * w.w + dtb[d + m];
      po[m] = softplusf(v);
    }
    *(float4*)(delta_g + ((size_t)b * LL + l0 + t) * DI + d) = ov;
  }
}

// ---------------- K3: local chunk scan (zero init) -> Aprod, Hend. 1024 blocks, no LDS.
__global__ __launch_bounds__(256) void k_scan1(
    const float* __restrict__ u_g, const float* __restrict__ delta_g,
    const float* __restrict__ Bm_g, const float* __restrict__ Alog,
    float* __restrict__ Aprod, float* __restrict__ Hend) {
  const int b = blockIdx.x >> 7;
  const int c = blockIdx.x & 127;
  const int l0 = c * TCH;
  const int d = threadIdx.x >> 1;
  const int n0 = (threadIdx.x & 1) * 8;
  float a[8], h[8], ap[8];
#pragma unroll
  for (int m = 0; m < 8; ++m) {
    a[m] = -__expf(Alog[d * NS + n0 + m]);
    h[m] = 0.f; ap[m] = 1.f;
  }
  for (int l = 0; l < TCH; ++l) {
    size_t tok = (size_t)b * LL + l0 + l;
    float dl = delta_g[tok * DI + d];
    float uu = u_g[tok * DI + d];
    float du = dl * uu;
    float4 b0 = *(const float4*)(Bm_g + tok * NS + n0);
    float4 b1 = *(const float4*)(Bm_g + tok * NS + n0 + 4);
    float bm[8] = {b0.x, b0.y, b0.z, b0.w, b1.x, b1.y, b1.z, b1.w};
#pragma unroll
    for (int m = 0; m < 8; ++m) {
      float dA = __expf(dl * a[m]);
      ap[m] *= dA;
      h[m] = fmaf(dA, h[m], du * bm[m]);
    }
  }
  size_t base = ((size_t)(b * NCH + c)) * 2048 + (size_t)threadIdx.x * 8;
  *(float4*)(Aprod + base)     = make_float4(ap[0], ap[1], ap[2], ap[3]);
  *(float4*)(Aprod + base + 4) = make_float4(ap[4], ap[5], ap[6], ap[7]);
  *(float4*)(Hend + base)      = make_float4(h[0], h[1], h[2], h[3]);
  *(float4*)(Hend + base + 4)  = make_float4(h[4], h[5], h[6], h[7]);
}

// ---------------- K4: 2-level prefix over 128 chunks per channel. 512 blocks x (8 seg x 32 ch).
// Hin may alias Aprod (each element read into registers before overwrite).
__global__ __launch_bounds__(256) void k_prefix2(
    const float* __restrict__ Aprod, const float* __restrict__ Hend,
    float* __restrict__ Hin) {
  __shared__ float sA[8][33], sB[8][33], sH[8][33];
  const int chl = threadIdx.x & 31;
  const int seg = threadIdx.x >> 5;
  const int ch = blockIdx.x * 32 + chl;
  const int b = ch >> 11, dn = ch & 2047;
  float av[16], bv[16];
  float A = 1.f, Bc = 0.f;
#pragma unroll
  for (int i = 0; i < 16; ++i) {
    int c = seg * 16 + i;
    size_t idx = ((size_t)(b * NCH + c)) * 2048 + dn;
    av[i] = Aprod[idx];
    bv[i] = Hend[idx];
    Bc = fmaf(av[i], Bc, bv[i]);
    A *= av[i];
  }
  sA[seg][chl] = A; sB[seg][chl] = Bc;
  __syncthreads();
  if (threadIdx.x < 32) {
    float h = 0.f;
#pragma unroll
    for (int s = 0; s < 8; ++s) {
      sH[s][threadIdx.x] = h;
      h = fmaf(sA[s][threadIdx.x], h, sB[s][threadIdx.x]);
    }
  }
  __syncthreads();
  float h = sH[seg][chl];
#pragma unroll
  for (int i = 0; i < 16; ++i) {
    int c = seg * 16 + i;
    size_t idx = ((size_t)(b * NCH + c)) * 2048 + dn;
    Hin[idx] = h;
    h = fmaf(av[i], h, bv[i]);
  }
}

// ---------------- K5: final scan with Hin; y = (sum h*C + u*D) * gate. 1024 blocks, no LDS.
__global__ __launch_bounds__(256) void k_scan2(
    const float* __restrict__ u_g, const float* __restrict__ delta_g,
    const float* __restrict__ Bm_g, const float* __restrict__ Cm_g,
    const float* __restrict__ gate, const float* __restrict__ Hin,
    const float* __restrict__ Alog, const float* __restrict__ Dw,
    float* __restrict__ y_g) {
  const int b = blockIdx.x >> 7;
  const int c = blockIdx.x & 127;
  const int l0 = c * TCH;
  const int d = threadIdx.x >> 1;
  const int n0 = (threadIdx.x & 1) * 8;
  float a[8], h[8];
  size_t hbase = ((size_t)(b * NCH + c)) * 2048 + (size_t)threadIdx.x * 8;
  float4 h0 = *(const float4*)(Hin + hbase);
  float4 h1 = *(const float4*)(Hin + hbase + 4);
  h[0] = h0.x; h[1] = h0.y; h[2] = h0.z; h[3] = h0.w;
  h[4] = h1.x; h[5] = h1.y; h[6] = h1.z; h[7] = h1.w;
#pragma unroll
  for (int m = 0; m < 8; ++m) a[m] = -__expf(Alog[d * NS + n0 + m]);
  float Dd = Dw[d];
  for (int l = 0; l < TCH; ++l) {
    size_t tok = (size_t)b * LL + l0 + l;
    float dl = delta_g[tok * DI + d];
    float uu = u_g[tok * DI + d];
    float du = dl * uu;
    float4 b0 = *(const float4*)(Bm_g + tok * NS + n0);
    float4 b1 = *(const float4*)(Bm_g + tok * NS + n0 + 4);
    float4 c0 = *(const float4*)(Cm_g + tok * NS + n0);
    float4 c1 = *(const float4*)(Cm_g + tok * NS + n0 + 4);
    float bm[8] = {b0.x, b0.y, b0.z, b0.w, b1.x, b1.y, b1.z, b1.w};
    float cm[8] = {c0.x, c0.y, c0.z, c0.w, c1.x, c1.y, c1.z, c1.w};
    float py = 0.f;
#pragma unroll
    for (int m = 0; m < 8; ++m) {
      float dA = __expf(dl * a[m]);
      h[m] = fmaf(dA, h[m], du * bm[m]);
      py = fmaf(h[m], cm[m], py);
    }
    py += __shfl_xor(py, 1);
    if (!(threadIdx.x & 1)) {
      y_g[tok * DI + d] = (py + uu * Dd) * gate[tok * DI + d];
    }
  }
}

// ---------------- K6: out = y @ Wout^T. 512 blocks: (b, 64 token-chunks of 64).
__global__ __launch_bounds__(256) void k_out(
    const float* __restrict__ y_g, const float* __restrict__ Wout,
    float* __restrict__ out) {
  __shared__ float ys[128][66];   // [k][t]
  __shared__ float wot[128][66];  // [k][o]
  const int b = blockIdx.x >> 6;
  const int l0 = (blockIdx.x & 63) * 64;
  const int tid = threadIdx.x;
  for (int i = 0; i < 8; ++i) {
    int idx = (i * 256 + tid) * 4;
    int t = idx >> 7, k = idx & 127;
    float4 v = *(const float4*)(y_g + ((size_t)b * LL + l0 + t) * DI + k);
    ys[k][t] = v.x; ys[k + 1][t] = v.y; ys[k + 2][t] = v.z; ys[k + 3][t] = v.w;
  }
  for (int i = 0; i < 8; ++i) {
    int idx = (i * 256 + tid) * 4;
    int o = idx >> 7, k = idx & 127;
    float4 v = *(const float4*)(Wout + idx);
    wot[k][o] = v.x; wot[k + 1][o] = v.y; wot[k + 2][o] = v.z; wot[k + 3][o] = v.w;
  }
  __syncthreads();
  const int t0 = (tid >> 4) * 4;
  const int o0 = (tid & 15) * 4;
  float acc[4][4];
#pragma unroll
  for (int i = 0; i < 4; ++i)
#pragma unroll
    for (int j = 0; j < 4; ++j) acc[i][j] = 0.f;
  for (int k = 0; k < 128; ++k) {
    float yv[4], wv[4];
    *(float4*)&yv[0] = *(const float4*)&ys[k][t0];
    *(float4*)&wv[0] = *(const float4*)&wot[k][o0];
#pragma unroll
    for (int i = 0; i < 4; ++i)
#pragma unroll
      for (int j = 0; j < 4; ++j) acc[i][j] = fmaf(yv[i], wv[j], acc[i][j]);
  }
  for (int i = 0; i < 4; ++i) {
    size_t row = (size_t)b * LL + l0 + t0 + i;
    *(float4*)(out + row * DM + o0) =
        make_float4(acc[i][0], acc[i][1], acc[i][2], acc[i][3]);
  }
}

extern "C" void kernel_launch(void* const* d_in, const int* in_sizes, int n_in,
                              void* d_out, int out_size, void* d_ws, size_t ws_size,
                              hipStream_t stream) {
  const float* x     = (const float*)d_in[0];
  // d_in[1] = latent (unused by reference)
  const float* Win   = (const float*)d_in[2];
  const float* convw = (const float*)d_in[3];
  const float* convb = (const float*)d_in[4];
  const float* xpw   = (const float*)d_in[5];
  const float* dtw   = (const float*)d_in[6];
  const float* dtb   = (const float*)d_in[7];
  const float* Wout  = (const float*)d_in[8];
  const float* Alog  = (const float*)d_in[9];
  const float* Dw    = (const float*)d_in[10];
  float* ws = (float*)d_ws;
  const size_t NT = (size_t)BB * LL;  // 32768 tokens
  float* upre    = ws;                         // 4.19M floats (reused as y_g later)
  float* gate    = upre + NT * DI;
  float* u_g     = gate + NT * DI;
  float* delta_g = u_g + NT * DI;
  float* Bm_g    = delta_g + NT * DI;
  float* Cm_g    = Bm_g + NT * NS;
  float* Aprod   = Cm_g + NT * NS;             // 2.10M floats (reused as Hin)
  float* Hend    = Aprod + (size_t)BB * NCH * DI * NS;
  float* Hin     = Aprod;                      // alias: safe (regs hold copies)
  float* y_g     = upre;                       // alias: upre dead after k_front
  float* outf = (float*)d_out;

  k_inproj<<<512, 256, 0, stream>>>(x, Win, upre, gate);
  k_front<<<512, 256, 0, stream>>>(upre, convw, convb, xpw, dtw, dtb,
                                   u_g, delta_g, Bm_g, Cm_g);
  k_scan1<<<1024, 256, 0, stream>>>(u_g, delta_g, Bm_g, Alog, Aprod, Hend);
  k_prefix2<<<512, 256, 0, stream>>>(Aprod, Hend, Hin);
  k_scan2<<<1024, 256, 0, stream>>>(u_g, delta_g, Bm_g, Cm_g, gate, Hin,
                                    Alog, Dw, y_g);
  k_out<<<512, 256, 0, stream>>>(y_g, Wout, outf);
}

// Round 3
// 125.963 us; speedup vs baseline: 1.6789x; 1.6065x over previous
//
#include <hip/hip_runtime.h>

#define BB 8
#define LL 4096
#define DM 64
#define DI 128
#define NS 16
#define TCH 32
#define NCH 128   // LL/TCH

__device__ __forceinline__ float siluf(float x) {
  return x / (1.f + __expf(-x));
}
__device__ __forceinline__ float softplusf(float x) {
  return x > 20.f ? x : log1pf(__expf(x));
}

// ---------------- K1: in_proj  xr = x @ Win^T ; upre = xr[:, :128]; gate = silu(xr[:, 128:])
// 512 blocks: (b, 32 token-chunks of 128, 2 j-halves). LDS 67.6KB -> 2 blocks/CU.
__global__ __launch_bounds__(256) void k_inproj(
    const float* __restrict__ x, const float* __restrict__ Win,
    float* __restrict__ upre, float* __restrict__ gate) {
  __shared__ float xs[64][132];   // [k][t]
  __shared__ float wT[64][132];   // [k][j]
  const int bid = blockIdx.x;
  const int jh = bid & 1;
  const int lc = (bid >> 1) & 31;
  const int b  = bid >> 6;
  const int l0 = lc * 128;
  const int tid = threadIdx.x;
  for (int i = 0; i < 8; ++i) {
    int idx = (i * 256 + tid) * 4;
    int t = idx >> 6, k = idx & 63;
    float4 v = *(const float4*)(x + ((size_t)b * LL + l0 + t) * DM + k);
    xs[k][t] = v.x; xs[k + 1][t] = v.y; xs[k + 2][t] = v.z; xs[k + 3][t] = v.w;
  }
  for (int i = 0; i < 8; ++i) {
    int idx = (i * 256 + tid) * 4;
    int j = idx >> 6, k = idx & 63;
    float4 v = *(const float4*)(Win + (size_t)(jh * 128 + j) * DM + k);
    wT[k][j] = v.x; wT[k + 1][j] = v.y; wT[k + 2][j] = v.z; wT[k + 3][j] = v.w;
  }
  __syncthreads();
  const int tg = (tid >> 4) * 8;
  const int j0 = (tid & 15) * 8;
  float acc[8][8];
#pragma unroll
  for (int i = 0; i < 8; ++i)
#pragma unroll
    for (int j = 0; j < 8; ++j) acc[i][j] = 0.f;
  for (int k = 0; k < 64; ++k) {
    float av[8], wv[8];
    *(float4*)&av[0] = *(const float4*)&xs[k][tg];
    *(float4*)&av[4] = *(const float4*)&xs[k][tg + 4];
    *(float4*)&wv[0] = *(const float4*)&wT[k][j0];
    *(float4*)&wv[4] = *(const float4*)&wT[k][j0 + 4];
#pragma unroll
    for (int i = 0; i < 8; ++i)
#pragma unroll
      for (int j = 0; j < 8; ++j) acc[i][j] = fmaf(av[i], wv[j], acc[i][j]);
  }
  for (int i = 0; i < 8; ++i) {
    size_t row = ((size_t)b * LL + l0 + tg + i);
    if (jh == 0) {
      *(float4*)(upre + row * DI + j0) =
          make_float4(acc[i][0], acc[i][1], acc[i][2], acc[i][3]);
      *(float4*)(upre + row * DI + j0 + 4) =
          make_float4(acc[i][4], acc[i][5], acc[i][6], acc[i][7]);
    } else {
      *(float4*)(gate + row * DI + j0) =
          make_float4(siluf(acc[i][0]), siluf(acc[i][1]), siluf(acc[i][2]), siluf(acc[i][3]));
      *(float4*)(gate + row * DI + j0 + 4) =
          make_float4(siluf(acc[i][4]), siluf(acc[i][5]), siluf(acc[i][6]), siluf(acc[i][7]));
    }
  }
}

// ---------------- K2 (v3): conv+silu -> u_g & usT(LDS); x_proj (wave-uniform rows, s_load
// weights) -> (drs, Bm, Cm); dt_proj+softplus -> delta_g. 512 blocks: (b, 64 chunks of 64 tok).
__global__ __launch_bounds__(256) void k_front(
    const float* __restrict__ upre,
    const float* __restrict__ convw, const float* __restrict__ convb,
    const float* __restrict__ xpw, const float* __restrict__ dtw,
    const float* __restrict__ dtb,
    float* __restrict__ u_g, float* __restrict__ delta_g,
    float* __restrict__ Bm_g, float* __restrict__ Cm_g) {
  __shared__ float usT[DI][68];   // [d][t], stride 68 -> conflict-free lane reads
  __shared__ float drs[64][4];
  const int b = blockIdx.x >> 6;
  const int l0 = (blockIdx.x & 63) * 64;
  const int tid = threadIdx.x;
  const size_t tokbase = (size_t)b * LL + l0;
  // Phase A: depthwise conv(4) + bias + silu. thread <-> (d, 4-token group)
  for (int i = 0; i < 8; ++i) {
    int idx = i * 256 + tid;
    int d = idx & 127;
    int t0 = (idx >> 7) * 4;
    float4 cw = *(const float4*)(convw + d * 4);
    float cb = convb[d];
    float p[7];
#pragma unroll
    for (int s = 0; s < 7; ++s) {
      int li = l0 + t0 - 3 + s;
      p[s] = (li >= 0) ? upre[((size_t)b * LL + li) * DI + d] : 0.f;
    }
    float4 uo;
    float* up = &uo.x;
#pragma unroll
    for (int j = 0; j < 4; ++j) {
      float a = cb;
      a = fmaf(p[j], cw.x, a);
      a = fmaf(p[j + 1], cw.y, a);
      a = fmaf(p[j + 2], cw.z, a);
      a = fmaf(p[j + 3], cw.w, a);
      up[j] = siluf(a);
      u_g[(tokbase + t0 + j) * DI + d] = up[j];
    }
    *(float4*)&usT[d][t0] = uo;
  }
  __syncthreads();
  // Phase B: x_proj. wave w computes rows [9w, 9w+9) for 64 tokens (lane = token).
  {
    const int wid = __builtin_amdgcn_readfirstlane(tid >> 6);
    const int lane = tid & 63;
    const size_t tok = tokbase + lane;
    float acc[9];
#pragma unroll
    for (int jj = 0; jj < 9; ++jj) acc[jj] = 0.f;
    const float* w0 = xpw + (size_t)(9 * wid) * DI;
    for (int k = 0; k < 128; k += 4) {
      float uv[4];
#pragma unroll
      for (int q = 0; q < 4; ++q) uv[q] = usT[k + q][lane];
#pragma unroll
      for (int jj = 0; jj < 9; ++jj) {
        const float* wr = w0 + jj * DI + k;
        acc[jj] = fmaf(uv[0], wr[0], acc[jj]);
        acc[jj] = fmaf(uv[1], wr[1], acc[jj]);
        acc[jj] = fmaf(uv[2], wr[2], acc[jj]);
        acc[jj] = fmaf(uv[3], wr[3], acc[jj]);
      }
    }
#pragma unroll
    for (int jj = 0; jj < 9; ++jj) {
      int j = 9 * wid + jj;
      if (j < 4) drs[lane][j] = acc[jj];
      else if (j < 20) Bm_g[tok * NS + (j - 4)] = acc[jj];
      else Cm_g[tok * NS + (j - 20)] = acc[jj];
    }
  }
  __syncthreads();
  // Phase C: dt_proj + softplus -> delta_g
  for (int i = 0; i < 8; ++i) {
    int idx = i * 256 + tid;
    int t = idx >> 5;
    int d = (idx & 31) * 4;
    float4 dr = *(const float4*)&drs[t][0];
    float4 ov;
    float* po = &ov.x;
#pragma unroll
    for (int m = 0; m < 4; ++m) {
      float4 w = *(const float4*)(dtw + (size_t)(d + m) * 4);
      float v = fmaf(dr.x, w.x, fmaf(dr.y, w.y, fmaf(dr.z, w.z, fmaf(dr.w, w.w, dtb[d + m]))));
      po[m] = softplusf(v);
    }
    *(float4*)(delta_g + (tokbase + t) * DI + d) = ov;
  }
}

// ---------------- K3: local chunk scan (zero init) -> Aprod, Hend. 1024 blocks, no LDS.
__global__ __launch_bounds__(256) void k_scan1(
    const float* __restrict__ u_g, const float* __restrict__ delta_g,
    const float* __restrict__ Bm_g, const float* __restrict__ Alog,
    float* __restrict__ Aprod, float* __restrict__ Hend) {
  const int b = blockIdx.x >> 7;
  const int c = blockIdx.x & 127;
  const int l0 = c * TCH;
  const int d = threadIdx.x >> 1;
  const int n0 = (threadIdx.x & 1) * 8;
  float a[8], h[8], ap[8];
#pragma unroll
  for (int m = 0; m < 8; ++m) {
    a[m] = -__expf(Alog[d * NS + n0 + m]);
    h[m] = 0.f; ap[m] = 1.f;
  }
  for (int l = 0; l < TCH; ++l) {
    size_t tok = (size_t)b * LL + l0 + l;
    float dl = delta_g[tok * DI + d];
    float uu = u_g[tok * DI + d];
    float du = dl * uu;
    float4 b0 = *(const float4*)(Bm_g + tok * NS + n0);
    float4 b1 = *(const float4*)(Bm_g + tok * NS + n0 + 4);
    float bm[8] = {b0.x, b0.y, b0.z, b0.w, b1.x, b1.y, b1.z, b1.w};
#pragma unroll
    for (int m = 0; m < 8; ++m) {
      float dA = __expf(dl * a[m]);
      ap[m] *= dA;
      h[m] = fmaf(dA, h[m], du * bm[m]);
    }
  }
  size_t base = ((size_t)(b * NCH + c)) * 2048 + (size_t)threadIdx.x * 8;
  *(float4*)(Aprod + base)     = make_float4(ap[0], ap[1], ap[2], ap[3]);
  *(float4*)(Aprod + base + 4) = make_float4(ap[4], ap[5], ap[6], ap[7]);
  *(float4*)(Hend + base)      = make_float4(h[0], h[1], h[2], h[3]);
  *(float4*)(Hend + base + 4)  = make_float4(h[4], h[5], h[6], h[7]);
}

// ---------------- K4: 2-level prefix over 128 chunks per channel. 512 blocks x (8 seg x 32 ch).
__global__ __launch_bounds__(256) void k_prefix2(
    const float* __restrict__ Aprod, const float* __restrict__ Hend,
    float* __restrict__ Hin) {
  __shared__ float sA[8][33], sB[8][33], sH[8][33];
  const int chl = threadIdx.x & 31;
  const int seg = threadIdx.x >> 5;
  const int ch = blockIdx.x * 32 + chl;
  const int b = ch >> 11, dn = ch & 2047;
  float av[16], bv[16];
  float A = 1.f, Bc = 0.f;
#pragma unroll
  for (int i = 0; i < 16; ++i) {
    int c = seg * 16 + i;
    size_t idx = ((size_t)(b * NCH + c)) * 2048 + dn;
    av[i] = Aprod[idx];
    bv[i] = Hend[idx];
    Bc = fmaf(av[i], Bc, bv[i]);
    A *= av[i];
  }
  sA[seg][chl] = A; sB[seg][chl] = Bc;
  __syncthreads();
  if (threadIdx.x < 32) {
    float h = 0.f;
#pragma unroll
    for (int s = 0; s < 8; ++s) {
      sH[s][threadIdx.x] = h;
      h = fmaf(sA[s][threadIdx.x], h, sB[s][threadIdx.x]);
    }
  }
  __syncthreads();
  float h = sH[seg][chl];
#pragma unroll
  for (int i = 0; i < 16; ++i) {
    int c = seg * 16 + i;
    size_t idx = ((size_t)(b * NCH + c)) * 2048 + dn;
    Hin[idx] = h;
    h = fmaf(av[i], h, bv[i]);
  }
}

// ---------------- K5: final scan with Hin; y = (sum h*C + u*D) * gate. 1024 blocks, no LDS.
__global__ __launch_bounds__(256) void k_scan2(
    const float* __restrict__ u_g, const float* __restrict__ delta_g,
    const float* __restrict__ Bm_g, const float* __restrict__ Cm_g,
    const float* __restrict__ gate, const float* __restrict__ Hin,
    const float* __restrict__ Alog, const float* __restrict__ Dw,
    float* __restrict__ y_g) {
  const int b = blockIdx.x >> 7;
  const int c = blockIdx.x & 127;
  const int l0 = c * TCH;
  const int d = threadIdx.x >> 1;
  const int n0 = (threadIdx.x & 1) * 8;
  float a[8], h[8];
  size_t hbase = ((size_t)(b * NCH + c)) * 2048 + (size_t)threadIdx.x * 8;
  float4 h0 = *(const float4*)(Hin + hbase);
  float4 h1 = *(const float4*)(Hin + hbase + 4);
  h[0] = h0.x; h[1] = h0.y; h[2] = h0.z; h[3] = h0.w;
  h[4] = h1.x; h[5] = h1.y; h[6] = h1.z; h[7] = h1.w;
#pragma unroll
  for (int m = 0; m < 8; ++m) a[m] = -__expf(Alog[d * NS + n0 + m]);
  float Dd = Dw[d];
  for (int l = 0; l < TCH; ++l) {
    size_t tok = (size_t)b * LL + l0 + l;
    float dl = delta_g[tok * DI + d];
    float uu = u_g[tok * DI + d];
    float du = dl * uu;
    float4 b0 = *(const float4*)(Bm_g + tok * NS + n0);
    float4 b1 = *(const float4*)(Bm_g + tok * NS + n0 + 4);
    float4 c0 = *(const float4*)(Cm_g + tok * NS + n0);
    float4 c1 = *(const float4*)(Cm_g + tok * NS + n0 + 4);
    float bm[8] = {b0.x, b0.y, b0.z, b0.w, b1.x, b1.y, b1.z, b1.w};
    float cm[8] = {c0.x, c0.y, c0.z, c0.w, c1.x, c1.y, c1.z, c1.w};
    float py = 0.f;
#pragma unroll
    for (int m = 0; m < 8; ++m) {
      float dA = __expf(dl * a[m]);
      h[m] = fmaf(dA, h[m], du * bm[m]);
      py = fmaf(h[m], cm[m], py);
    }
    py += __shfl_xor(py, 1);
    if (!(threadIdx.x & 1)) {
      y_g[tok * DI + d] = (py + uu * Dd) * gate[tok * DI + d];
    }
  }
}

// ---------------- K6: out = y @ Wout^T. 512 blocks: (b, 64 token-chunks of 64).
__global__ __launch_bounds__(256) void k_out(
    const float* __restrict__ y_g, const float* __restrict__ Wout,
    float* __restrict__ out) {
  __shared__ float ys[128][66];   // [k][t]
  __shared__ float wot[128][66];  // [k][o]
  const int b = blockIdx.x >> 6;
  const int l0 = (blockIdx.x & 63) * 64;
  const int tid = threadIdx.x;
  for (int i = 0; i < 8; ++i) {
    int idx = (i * 256 + tid) * 4;
    int t = idx >> 7, k = idx & 127;
    float4 v = *(const float4*)(y_g + ((size_t)b * LL + l0 + t) * DI + k);
    ys[k][t] = v.x; ys[k + 1][t] = v.y; ys[k + 2][t] = v.z; ys[k + 3][t] = v.w;
  }
  for (int i = 0; i < 8; ++i) {
    int idx = (i * 256 + tid) * 4;
    int o = idx >> 7, k = idx & 127;
    float4 v = *(const float4*)(Wout + idx);
    wot[k][o] = v.x; wot[k + 1][o] = v.y; wot[k + 2][o] = v.z; wot[k + 3][o] = v.w;
  }
  __syncthreads();
  const int t0 = (tid >> 4) * 4;
  const int o0 = (tid & 15) * 4;
  float acc[4][4];
#pragma unroll
  for (int i = 0; i < 4; ++i)
#pragma unroll
    for (int j = 0; j < 4; ++j) acc[i][j] = 0.f;
  for (int k = 0; k < 128; ++k) {
    float yv[4], wv[4];
    *(float4*)&yv[0] = *(const float4*)&ys[k][t0];
    *(float4*)&wv[0] = *(const float4*)&wot[k][o0];
#pragma unroll
    for (int i = 0; i < 4; ++i)
#pragma unroll
      for (int j = 0; j < 4; ++j) acc[i][j] = fmaf(yv[i], wv[j], acc[i][j]);
  }
  for (int i = 0; i < 4; ++i) {
    size_t row = (size_t)b * LL + l0 + t0 + i;
    *(float4*)(out + row * DM + o0) =
        make_float4(acc[i][0], acc[i][1], acc[i][2], acc[i][3]);
  }
}

extern "C" void kernel_launch(void* const* d_in, const int* in_sizes, int n_in,
                              void* d_out, int out_size, void* d_ws, size_t ws_size,
                              hipStream_t stream) {
  const float* x     = (const float*)d_in[0];
  // d_in[1] = latent (unused by reference)
  const float* Win   = (const float*)d_in[2];
  const float* convw = (const float*)d_in[3];
  const float* convb = (const float*)d_in[4];
  const float* xpw   = (const float*)d_in[5];
  const float* dtw   = (const float*)d_in[6];
  const float* dtb   = (const float*)d_in[7];
  const float* Wout  = (const float*)d_in[8];
  const float* Alog  = (const float*)d_in[9];
  const float* Dw    = (const float*)d_in[10];
  float* ws = (float*)d_ws;
  const size_t NT = (size_t)BB * LL;  // 32768 tokens
  float* upre    = ws;                         // reused as y_g later
  float* gate    = upre + NT * DI;
  float* u_g     = gate + NT * DI;
  float* delta_g = u_g + NT * DI;
  float* Bm_g    = delta_g + NT * DI;
  float* Cm_g    = Bm_g + NT * NS;
  float* Aprod   = Cm_g + NT * NS;             // reused as Hin
  float* Hend    = Aprod + (size_t)BB * NCH * DI * NS;
  float* Hin     = Aprod;                      // alias: safe (regs hold copies)
  float* y_g     = upre;                       // alias: upre dead after k_front
  float* outf = (float*)d_out;

  k_inproj<<<512, 256, 0, stream>>>(x, Win, upre, gate);
  k_front<<<512, 256, 0, stream>>>(upre, convw, convb, xpw, dtw, dtb,
                                   u_g, delta_g, Bm_g, Cm_g);
  k_scan1<<<1024, 256, 0, stream>>>(u_g, delta_g, Bm_g, Alog, Aprod, Hend);
  k_prefix2<<<512, 256, 0, stream>>>(Aprod, Hend, Hin);
  k_scan2<<<1024, 256, 0, stream>>>(u_g, delta_g, Bm_g, Cm_g, gate, Hin,
                                    Alog, Dw, y_g);
  k_out<<<512, 256, 0, stream>>>(y_g, Wout, outf);
}